// Round 5
// baseline (247.110 us; speedup 1.0000x reference)
//
#include <hip/hip_runtime.h>
#include <hip/hip_bf16.h>
#include <math.h>

#define NTOK 4096
#define DIM 2048
#define NHEAD 1002
#define NCAT 1664
#define C0LO 1000
#define C0HI 10000
#define OSZ0 9000
#define OSZ1 40257
#define H0S 512
#define H1S 128
#define JS0 16
#define JS1 16
#define HEADBLKS 8
#define NB0 512              // tail0 blocks (32 tok-blocks x 16 j-slices)
#define NT0 71               // ceil(9000/128)
#define NT1 315              // ceil(40257/128)

typedef __attribute__((ext_vector_type(4))) short short4v;
typedef __attribute__((ext_vector_type(8))) short short8v;
typedef __attribute__((ext_vector_type(4))) float f32x4;
typedef __hip_bfloat16 bf16;

#define GLOBAL_AS __attribute__((address_space(1)))
#define LDS_AS __attribute__((address_space(3)))

#define RAW_BAR() __builtin_amdgcn_s_barrier()
#define SCHED_FENCE() __builtin_amdgcn_sched_barrier(0)
#define WAIT_VM(N) asm volatile("s_waitcnt vmcnt(" #N ")" ::: "memory")
#define WAIT_LGKM0() asm volatile("s_waitcnt lgkmcnt(0)" ::: "memory")

// ---------- fused fp32->bf16 convert + Wcat concat ----------
__global__ __launch_bounds__(256) void cvt_all(
    const float* __restrict__ x, const float* __restrict__ W_head,
    const float* __restrict__ W1_0, const float* __restrict__ W1_1,
    const float* __restrict__ W2_0, const float* __restrict__ W2_1,
    bf16* __restrict__ xb, bf16* __restrict__ Wcat,
    bf16* __restrict__ W20b, bf16* __restrict__ W21b) {
  const long NX = (long)NTOK * DIM / 8;
  const long NC = (long)NCAT * DIM / 8;
  const long N20 = (long)OSZ0 * H0S / 8;
  const long N21 = (long)OSZ1 * H1S / 8;
  long gid = (long)blockIdx.x * 256 + threadIdx.x;
  const float* src = nullptr;
  bf16* dst;
  if (gid < NX) {
    src = x + gid * 8; dst = xb + gid * 8;
  } else if (gid < NX + NC) {
    long o = (gid - NX) * 8;
    int row = (int)(o >> 11), k = (int)(o & 2047);
    dst = Wcat + o;
    if (row < NHEAD) src = W_head + (long)row * DIM + k;
    else if (row < 1024) src = nullptr;              // zero padding rows
    else if (row < 1536) src = W1_0 + (long)(row - 1024) * DIM + k;
    else src = W1_1 + (long)(row - 1536) * DIM + k;
  } else if (gid < NX + NC + N20) {
    long o = (gid - NX - NC) * 8; src = W2_0 + o; dst = W20b + o;
  } else if (gid < NX + NC + N20 + N21) {
    long o = (gid - NX - NC - N20) * 8; src = W2_1 + o; dst = W21b + o;
  } else {
    return;
  }
  union { short8v v; bf16 h[8]; } u;
  if (src) {
    float4 a = *reinterpret_cast<const float4*>(src);
    float4 b = *reinterpret_cast<const float4*>(src + 4);
    u.h[0] = __float2bfloat16(a.x); u.h[1] = __float2bfloat16(a.y);
    u.h[2] = __float2bfloat16(a.z); u.h[3] = __float2bfloat16(a.w);
    u.h[4] = __float2bfloat16(b.x); u.h[5] = __float2bfloat16(b.y);
    u.h[6] = __float2bfloat16(b.z); u.h[7] = __float2bfloat16(b.w);
  } else {
#pragma unroll
    for (int e = 0; e < 8; ++e) u.h[e] = __float2bfloat16(0.f);
  }
  *reinterpret_cast<short8v*>(dst) = u.v;
}

// ---------- 128B-row staging (BK=64 slice), verified R2/R3 ----------
__device__ __forceinline__ void stage_tile(const bf16* __restrict__ g, int row0,
                                           int maxrow, int ld, int k0,
                                           char* lds, int wave, int lane) {
#pragma unroll
  for (int c = 0; c < 4; ++c) {
    int rbase = wave * 32 + c * 8;
    int row = rbase + (lane >> 3);
    int grow = row0 + row;
    grow = grow < maxrow ? grow : maxrow;
    int slot = (lane & 7) ^ (row & 7);
    const bf16* src = g + (size_t)grow * ld + k0 + slot * 8;
    __builtin_amdgcn_global_load_lds((const GLOBAL_AS unsigned int*)src,
                                     (LDS_AS unsigned int*)(lds + rbase * 128),
                                     16, 0, 0);
  }
}

__device__ __forceinline__ short8v read_frag(const char* lds, int row, int kk, int lane) {
  int g = lane >> 4;
  int r7 = row & 7;
  int b1 = kk * 64 + g * 8;
  int b2 = b1 + 32;
  b1 = ((b1 >> 4) ^ r7) * 16 + (b1 & 15);
  b2 = ((b2 >> 4) ^ r7) * 16 + (b2 & 15);
  const char* p = lds + row * 128;
  short4v lo = *reinterpret_cast<const short4v*>(p + b1);
  short4v hi = *reinterpret_cast<const short4v*>(p + b2);
  return __builtin_shufflevector(lo, hi, 0, 1, 2, 3, 4, 5, 6, 7);
}

// ---------- 256B-row staging (whole K=128 tile, tail1) ----------
__device__ __forceinline__ void stage_tile256(const bf16* __restrict__ g, int row0,
                                              int maxrow, int ld,
                                              char* lds, int wave, int lane) {
#pragma unroll
  for (int c = 0; c < 8; ++c) {
    int rbase = wave * 32 + c * 4;
    int row = rbase + (lane >> 4);
    int grow = row0 + row;
    grow = grow < maxrow ? grow : maxrow;
    int slot = (lane & 15) ^ (row & 7);
    const bf16* src = g + (size_t)grow * ld + slot * 8;
    __builtin_amdgcn_global_load_lds((const GLOBAL_AS unsigned int*)src,
                                     (LDS_AS unsigned int*)(lds + rbase * 256),
                                     16, 0, 0);
  }
}

__device__ __forceinline__ short8v read_frag256(const char* lds, int row, int kk, int lane) {
  int g = lane >> 4;
  int r7 = row & 7;
  int b1 = kk * 64 + g * 8;
  int b2 = b1 + 32;
  b1 = (((b1 >> 4) ^ r7) << 4) | (b1 & 15);
  b2 = (((b2 >> 4) ^ r7) << 4) | (b2 & 15);
  const char* p = lds + row * 256;
  short4v lo = *reinterpret_cast<const short4v*>(p + b1);
  short4v hi = *reinterpret_cast<const short4v*>(p + b2);
  return __builtin_shufflevector(lo, hi, 0, 1, 2, 3, 4, 5, 6, 7);
}

// shared sum-exp tree reduce + partial-sum write (layout identical R2/R3)
__device__ __forceinline__ void reduce_write_ps(float srun[4][4], float* reds,
                                                float* ps, int slice, int tok0,
                                                int lane, int wr, int wc) {
#pragma unroll
  for (int off = 1; off < 16; off <<= 1)
#pragma unroll
    for (int m = 0; m < 4; ++m)
#pragma unroll
      for (int r = 0; r < 4; ++r) srun[m][r] += __shfl_xor(srun[m][r], off);
  __syncthreads();
  if (wc == 0 && (lane & 15) == 0) {
#pragma unroll
    for (int m = 0; m < 4; ++m)
#pragma unroll
      for (int r = 0; r < 4; ++r)
        reds[wr * 64 + m * 16 + (lane >> 4) * 4 + r] = srun[m][r];
  }
  __syncthreads();
  if (wc == 1 && (lane & 15) == 0) {
#pragma unroll
    for (int m = 0; m < 4; ++m)
#pragma unroll
      for (int r = 0; r < 4; ++r) {
        int row = wr * 64 + m * 16 + (lane >> 4) * 4 + r;
        ps[(size_t)slice * NTOK + tok0 + row] = reds[row] + srun[m][r];
      }
  }
}

// ---------- tail0 path: dbuf A+B, flattened (j,k), counted vmcnt ----------
__device__ void tail0_path(const bf16* __restrict__ Ab, const bf16* __restrict__ W2b,
                           float* __restrict__ ps, int bid, char* lds) {
  char* Abuf[2] = {lds, lds + 16384};
  char* Bbuf[2] = {lds + 32768, lds + 49152};
  float* reds = (float*)(lds + 65536);
  int tid = threadIdx.x;
  int lane = tid & 63, wave = tid >> 6;
  int wr = wave >> 1, wc = wave & 1;
  int tb = bid & 31, ys = bid >> 5;
  int tok0 = tb * 128;
  int t_lo = (NT0 * ys) / JS0, t_hi = (NT0 * (ys + 1)) / JS0;
  int niter = (t_hi - t_lo) * 8;   // 8 k-steps per j-tile (H=512/64)

  // batch it: A slice k0=(it&7)*64 ; B rows jt=t_lo+(it>>3), same k0
  stage_tile(Ab, tok0, NTOK - 1, H0S, (0 & 7) * 64, Abuf[0], wave, lane);
  stage_tile(W2b, (t_lo + 0) * 128, OSZ0 - 1, H0S, 0 * 64, Bbuf[0], wave, lane);
  if (niter > 1) {
    stage_tile(Ab, tok0, NTOK - 1, H0S, 1 * 64, Abuf[1], wave, lane);
    stage_tile(W2b, t_lo * 128, OSZ0 - 1, H0S, 1 * 64, Bbuf[1], wave, lane);
  }
  float srun[4][4] = {};
  f32x4 acc[4][4];
  for (int it = 0; it < niter; ++it) {
    char* Ac = Abuf[it & 1];
    char* Bc = Bbuf[it & 1];
    if (it + 1 < niter) { WAIT_VM(8); } else { WAIT_VM(0); }
    SCHED_FENCE();
    RAW_BAR();
    int kst = it & 7;
    if (kst == 0) {
#pragma unroll
      for (int m = 0; m < 4; ++m)
#pragma unroll
        for (int n = 0; n < 4; ++n) acc[m][n] = f32x4{0.f, 0.f, 0.f, 0.f};
    }
#pragma unroll
    for (int kk = 0; kk < 2; ++kk) {
      short8v af[4], bfr[4];
#pragma unroll
      for (int m = 0; m < 4; ++m)
        af[m] = read_frag(Ac, wr * 64 + m * 16 + (lane & 15), kk, lane);
#pragma unroll
      for (int n = 0; n < 4; ++n)
        bfr[n] = read_frag(Bc, wc * 64 + n * 16 + (lane & 15), kk, lane);
#pragma unroll
      for (int m = 0; m < 4; ++m)
#pragma unroll
        for (int n = 0; n < 4; ++n)
          acc[m][n] = __builtin_amdgcn_mfma_f32_16x16x32_bf16(af[m], bfr[n], acc[m][n], 0, 0, 0);
    }
    if (kst == 7) {
      int j0 = (t_lo + (it >> 3)) * 128;
#pragma unroll
      for (int m = 0; m < 4; ++m)
#pragma unroll
        for (int n = 0; n < 4; ++n) {
          int col = j0 + wc * 64 + n * 16 + (lane & 15);
          if (col < OSZ0) {
#pragma unroll
            for (int r = 0; r < 4; ++r) srun[m][r] += __expf(acc[m][n][r]);
          }
        }
    }
    SCHED_FENCE();
    RAW_BAR();
    if (it + 2 < niter) {
      int it2 = it + 2;
      stage_tile(Ab, tok0, NTOK - 1, H0S, (it2 & 7) * 64, Ac, wave, lane);
      stage_tile(W2b, (t_lo + (it2 >> 3)) * 128, OSZ0 - 1, H0S, (it2 & 7) * 64, Bc, wave, lane);
    }
  }
  reduce_write_ps(srun, reds, ps, ys, tok0, lane, wr, wc);
}

// ---------- tail1 path: A-in-regs, dbuf B stream (R3-verified) ----------
__device__ void tail1_path(const bf16* __restrict__ Ab, const bf16* __restrict__ W2b,
                           float* __restrict__ ps, int bid, char* lds) {
  char* buf0 = lds;             // 32 KB
  char* buf1 = lds + 32768;     // 32 KB
  float* reds = (float*)(lds + 65536);
  int tid = threadIdx.x;
  int lane = tid & 63, wave = tid >> 6;
  int wr = wave >> 1, wc = wave & 1;
  int tb = bid & 31, ys = bid >> 5;
  int tok0 = tb * 128;
  int t_lo = (NT1 * ys) / JS1, t_hi = (NT1 * (ys + 1)) / JS1;
  int nt = t_hi - t_lo;

  stage_tile256(Ab, tok0, NTOK - 1, H1S, buf1, wave, lane);
  WAIT_VM(0); SCHED_FENCE();
  RAW_BAR();
  short8v afr[4][4];
#pragma unroll
  for (int kk = 0; kk < 4; ++kk)
#pragma unroll
    for (int m = 0; m < 4; ++m)
      afr[kk][m] = read_frag256(buf1, wr * 64 + m * 16 + (lane & 15), kk, lane);
  stage_tile256(W2b, t_lo * 128, OSZ1 - 1, H1S, buf0, wave, lane);
  WAIT_LGKM0(); SCHED_FENCE();   // A-frag reads done before buf1 reuse
  RAW_BAR();
  if (nt > 1) stage_tile256(W2b, (t_lo + 1) * 128, OSZ1 - 1, H1S, buf1, wave, lane);

  float srun[4][4] = {};
  for (int i = 0; i < nt; ++i) {
    char* cur = (i & 1) ? buf1 : buf0;
    if (i + 1 < nt) { WAIT_VM(8); } else { WAIT_VM(0); }
    SCHED_FENCE();
    RAW_BAR();
    int j0 = (t_lo + i) * 128;
    f32x4 acc[4][4] = {};
#pragma unroll
    for (int kk = 0; kk < 4; ++kk) {
      short8v bfr[4];
#pragma unroll
      for (int n = 0; n < 4; ++n)
        bfr[n] = read_frag256(cur, wc * 64 + n * 16 + (lane & 15), kk, lane);
#pragma unroll
      for (int m = 0; m < 4; ++m)
#pragma unroll
        for (int n = 0; n < 4; ++n)
          acc[m][n] = __builtin_amdgcn_mfma_f32_16x16x32_bf16(afr[kk][m], bfr[n], acc[m][n], 0, 0, 0);
    }
#pragma unroll
    for (int m = 0; m < 4; ++m)
#pragma unroll
      for (int n = 0; n < 4; ++n) {
        int col = j0 + wc * 64 + n * 16 + (lane & 15);
        if (col < OSZ1) {
#pragma unroll
          for (int r = 0; r < 4; ++r) srun[m][r] += __expf(acc[m][n][r]);
        }
      }
    SCHED_FENCE();
    RAW_BAR();
    if (i + 2 < nt) stage_tile256(W2b, (t_lo + i + 2) * 128, OSZ1 - 1, H1S, cur, wave, lane);
  }
  reduce_write_ps(srun, reds, ps, ys, tok0, lane, wr, wc);
}

// ---------- merged tails dispatch ----------
__global__ __launch_bounds__(256, 2) void tails_fused(
    const bf16* __restrict__ h0b, const bf16* __restrict__ W20b,
    const bf16* __restrict__ h1b, const bf16* __restrict__ W21b,
    float* __restrict__ ps0, float* __restrict__ ps1) {
  __shared__ __align__(16) char lds[66048];
  int bid = blockIdx.x;
  if (bid < NB0) tail0_path(h0b, W20b, ps0, bid, lds);
  else           tail1_path(h1b, W21b, ps1, bid - NB0, lds);
}

// ---------- fused projection GEMM, dbuf counted-vmcnt ----------
// Body in a __device__ function taking lds as a runtime pointer: building
// pointer aggregates directly from the __shared__ symbol trips an
// "unsupported static initializer" addrspacecast error on gfx950.
__device__ void proj_gemm_body(
    const bf16* __restrict__ A, const bf16* __restrict__ B,
    float* __restrict__ head, float* __restrict__ h0, bf16* __restrict__ h0b,
    float* __restrict__ h1, bf16* __restrict__ h1b, float* __restrict__ ps_head,
    char* lds) {
  char* Abuf[2] = {lds, lds + 16384};
  char* Bbuf[2] = {lds + 32768, lds + 49152};
  float* reds = (float*)(lds + 65536);
  int tid = threadIdx.x;
  int lane = tid & 63, wave = tid >> 6;
  int wr = wave >> 1, wc = wave & 1;
  int row0 = blockIdx.y * 128, col0 = blockIdx.x * 128;
  const int NIT = DIM / 64;  // 32
  stage_tile(A, row0, NTOK - 1, DIM, 0, Abuf[0], wave, lane);
  stage_tile(B, col0, NCAT - 1, DIM, 0, Bbuf[0], wave, lane);
  stage_tile(A, row0, NTOK - 1, DIM, 64, Abuf[1], wave, lane);
  stage_tile(B, col0, NCAT - 1, DIM, 64, Bbuf[1], wave, lane);
  f32x4 acc[4][4] = {};
  for (int it = 0; it < NIT; ++it) {
    char* Ac = Abuf[it & 1];
    char* Bc = Bbuf[it & 1];
    if (it + 1 < NIT) { WAIT_VM(8); } else { WAIT_VM(0); }
    SCHED_FENCE();
    RAW_BAR();
#pragma unroll
    for (int kk = 0; kk < 2; ++kk) {
      short8v af[4], bfr[4];
#pragma unroll
      for (int m = 0; m < 4; ++m)
        af[m] = read_frag(Ac, wr * 64 + m * 16 + (lane & 15), kk, lane);
#pragma unroll
      for (int n = 0; n < 4; ++n)
        bfr[n] = read_frag(Bc, wc * 64 + n * 16 + (lane & 15), kk, lane);
#pragma unroll
      for (int m = 0; m < 4; ++m)
#pragma unroll
        for (int n = 0; n < 4; ++n)
          acc[m][n] = __builtin_amdgcn_mfma_f32_16x16x32_bf16(af[m], bfr[n], acc[m][n], 0, 0, 0);
    }
    SCHED_FENCE();
    RAW_BAR();
    if (it + 2 < NIT) {
      stage_tile(A, row0, NTOK - 1, DIM, (it + 2) * 64, Ac, wave, lane);
      stage_tile(B, col0, NCAT - 1, DIM, (it + 2) * 64, Bc, wave, lane);
    }
  }
  float srun[4][4] = {};
#pragma unroll
  for (int m = 0; m < 4; ++m) {
    int row = row0 + wr * 64 + m * 16 + (lane >> 4) * 4;
#pragma unroll
    for (int n = 0; n < 4; ++n) {
      int col = col0 + wc * 64 + n * 16 + (lane & 15);
#pragma unroll
      for (int r = 0; r < 4; ++r) {
        float v = acc[m][n][r];
        if (col < NHEAD) {
          head[(size_t)(row + r) * NHEAD + col] = v;
          srun[m][r] += __expf(v);
        } else if (col >= 1024 && col < 1536) {
          h0[(size_t)(row + r) * H0S + (col - 1024)] = v;
          h0b[(size_t)(row + r) * H0S + (col - 1024)] = __float2bfloat16(v);
        } else if (col >= 1536) {
          h1[(size_t)(row + r) * H1S + (col - 1536)] = v;
          h1b[(size_t)(row + r) * H1S + (col - 1536)] = __float2bfloat16(v);
        }
      }
    }
  }
  if (blockIdx.x < HEADBLKS) {
    reduce_write_ps(srun, reds, ps_head, blockIdx.x, row0, lane, wr, wc);
  }
}

__global__ __launch_bounds__(256, 2) void proj_gemm(
    const bf16* __restrict__ A, const bf16* __restrict__ B,
    float* __restrict__ head, float* __restrict__ h0, bf16* __restrict__ h0b,
    float* __restrict__ h1, bf16* __restrict__ h1b, float* __restrict__ ps_head) {
  __shared__ __align__(16) char lds[66048];
  proj_gemm_body(A, B, head, h0, h0b, h1, h1b, ps_head, lds);
}

// ---------- finalize: one wave per token ----------
__global__ __launch_bounds__(256) void finalize2(
    const int* __restrict__ target, const float* __restrict__ head,
    const float* __restrict__ ps_head,
    const float* __restrict__ h0, const float* __restrict__ h1,
    const float* __restrict__ W2_0, const float* __restrict__ W2_1,
    const float* __restrict__ ps0, const float* __restrict__ ps1,
    float* __restrict__ out) {
  int warp = threadIdx.x >> 6, lane = threadIdx.x & 63;
  int i = blockIdx.x * 4 + warp;
  if (i >= NTOK) return;
  int t = target[i];
  float sh = 0.f;
#pragma unroll
  for (int s = 0; s < HEADBLKS; ++s) sh += ps_head[(size_t)s * NTOK + i];
  float lse_head = logf(sh);
  float res;
  if (t < C0LO) {
    res = head[(size_t)i * NHEAD + t] - lse_head;
  } else {
    int c = (t < C0HI) ? 0 : 1;
    int H = c ? H1S : H0S;
    int low = c ? C0HI : C0LO;
    const float* hv = (c ? h1 : h0) + (size_t)i * H;
    const float* wv = (c ? W2_1 : W2_0) + (size_t)(t - low) * H;
    float p = 0.f;
    for (int k = lane * 4; k < H; k += 256) {
      float4 a = *reinterpret_cast<const float4*>(hv + k);
      float4 b = *reinterpret_cast<const float4*>(wv + k);
      p += a.x * b.x + a.y * b.y + a.z * b.z + a.w * b.w;
    }
#pragma unroll
    for (int off = 32; off > 0; off >>= 1) p += __shfl_xor(p, off);
    const float* ps = c ? ps1 : ps0;
    float S = 0.f;
    for (int s = 0; s < JS0; ++s) S += ps[(size_t)s * NTOK + i];
    float cl = head[(size_t)i * NHEAD + C0LO + c];
    res = (cl - lse_head) + (p - logf(S));
  }
  if (lane == 0) out[i] = res;
}

__global__ __launch_bounds__(256) void loss_kernel(float* __restrict__ out) {
  __shared__ float red[256];
  int tid = threadIdx.x;
  float s = 0.f;
  for (int j = tid; j < NTOK; j += 256) s += out[j];
  red[tid] = s; __syncthreads();
  for (int off = 128; off > 0; off >>= 1) {
    if (tid < off) red[tid] += red[tid + off];
    __syncthreads();
  }
  if (tid == 0) out[NTOK] = -red[0] / (float)NTOK;
}

extern "C" void kernel_launch(void* const* d_in, const int* in_sizes, int n_in,
                              void* d_out, int out_size, void* d_ws, size_t ws_size,
                              hipStream_t stream) {
  (void)in_sizes; (void)n_in; (void)out_size; (void)ws_size;
  const float* x = (const float*)d_in[0];
  const int* target = (const int*)d_in[1];
  const float* W_head = (const float*)d_in[2];
  const float* W1_0 = (const float*)d_in[3];
  const float* W2_0 = (const float*)d_in[4];
  const float* W1_1 = (const float*)d_in[5];
  const float* W2_1 = (const float*)d_in[6];
  float* out = (float*)d_out;

  char* w = (char*)d_ws;
  size_t off = 0;
  auto alloc = [&](size_t bytes) -> void* {
    void* p = w + off;
    off = (off + bytes + 255) & ~(size_t)255;
    return p;
  };
  bf16* xb   = (bf16*)alloc((size_t)NTOK * DIM * 2);
  bf16* Wcat = (bf16*)alloc((size_t)NCAT * DIM * 2);
  bf16* W20b = (bf16*)alloc((size_t)OSZ0 * H0S * 2);
  bf16* W21b = (bf16*)alloc((size_t)OSZ1 * H1S * 2);
  float* head = (float*)alloc((size_t)NTOK * NHEAD * 4);
  float* h0   = (float*)alloc((size_t)NTOK * H0S * 4);
  bf16*  h0b  = (bf16*)alloc((size_t)NTOK * H0S * 2);
  float* h1   = (float*)alloc((size_t)NTOK * H1S * 4);
  bf16*  h1b  = (bf16*)alloc((size_t)NTOK * H1S * 2);
  float* ps_head = (float*)alloc((size_t)HEADBLKS * NTOK * 4);
  float* ps0 = (float*)alloc((size_t)JS0 * NTOK * 4);
  float* ps1 = (float*)alloc((size_t)JS1 * NTOK * 4);

  dim3 blk(256);
  const long TOT8 = (long)NTOK * DIM / 8 + (long)NCAT * DIM / 8 +
                    (long)OSZ0 * H0S / 8 + (long)OSZ1 * H1S / 8;
  cvt_all<<<dim3((unsigned)((TOT8 + 255) / 256)), blk, 0, stream>>>(
      x, W_head, W1_0, W1_1, W2_0, W2_1, xb, Wcat, W20b, W21b);

  proj_gemm<<<dim3(NCAT / 128, NTOK / 128), blk, 0, stream>>>(
      xb, Wcat, head, h0, h0b, h1, h1b, ps_head);

  tails_fused<<<dim3(NB0 + 32 * JS1), blk, 0, stream>>>(h0b, W20b, h1b, W21b, ps0, ps1);

  finalize2<<<dim3(NTOK / 4), blk, 0, stream>>>(target, head, ps_head, h0, h1,
                                                W2_0, W2_1, ps0, ps1, out);
  loss_kernel<<<1, blk, 0, stream>>>(out);
}